// Round 6
// baseline (139.811 us; speedup 1.0000x reference)
//
#include <hip/hip_runtime.h>
#include <hip/hip_bf16.h>
#include <math.h>

typedef _Float16 f16x8 __attribute__((ext_vector_type(8)));
typedef _Float16 f16x4 __attribute__((ext_vector_type(4)));
typedef float f32x4 __attribute__((ext_vector_type(4)));
typedef float f32x16 __attribute__((ext_vector_type(16)));

#define LDH 264  // 256 + 8 f16 pad -> row stride 132 dwords (4-bank rotation)

// ---------------- fused prep: blocks 0..383 transpose W, 384..543 A/B proj -----
// W frag layout: frag = (L*8+cg)*16+ks ; col = cg*32+(l&31) ; k = ks*16+(l>>5)*8+e
__global__ void prep(const float* __restrict__ x, const float* __restrict__ W1,
                     const float* __restrict__ b1,
                     const float* __restrict__ W2, const float* __restrict__ W3,
                     const float* __restrict__ W4,
                     float* __restrict__ A, float* __restrict__ B,
                     _Float16* __restrict__ Wt) {
    __shared__ float xs[258 * 4];
    if (blockIdx.x < 384) {
        int blk = blockIdx.x, t = threadIdx.x;
        int ks = blk & 15, cg = (blk >> 4) & 7, L = blk >> 7;
        int l = t >> 3, e = t & 7;
        int col = cg * 32 + (l & 31);
        int k   = ks * 16 + (l >> 5) * 8 + e;
        const float* W = (L == 0) ? W2 : (L == 1) ? W3 : W4;
        Wt[blk * 512 + t] = (_Float16)W[k * 256 + col];
        return;
    }
    int blk = blockIdx.x - 384;
    int bs = blk >> 2, pg = blk & 3;           // 4 p-values per block
    for (int i = threadIdx.x; i < 1024; i += 512) {
        int c = i >> 2, pp = i & 3;
        xs[i] = x[bs * 4096 + c * 16 + pg * 4 + pp];
    }
    if (threadIdx.x < 8) {
        int pp = threadIdx.x & 3, c = 256 + (threadIdx.x >> 2);
        int p = pg * 4 + pp;
        xs[c * 4 + pp] = (float)((c == 256) ? (p >> 2) : (p & 3)) * 0.25f;
    }
    __syncthreads();
    int half = threadIdx.x >> 8;               // 0 -> A, 1 -> B
    int col  = threadIdx.x & 255;
    float acc[4] = {0.f, 0.f, 0.f, 0.f};
    const float* Wp = W1 + half * 258 * 256 + col;
    for (int c = 0; c < 258; c++) {
        float w = Wp[c * 256];
#pragma unroll
        for (int pp = 0; pp < 4; pp++) acc[pp] += xs[c * 4 + pp] * w;
    }
    float* out = half ? B : A;
    float bias = half ? 0.f : b1[col];         // fold b1 into A once
#pragma unroll
    for (int pp = 0; pp < 4; pp++)
        out[(bs * 16 + pg * 4 + pp) * 256 + col] = acc[pp] + bias;
}

// ---------------- the big fused kernel ------------------------------------------
// grid 1600 = (b,s1,s2) x 2 row-halves; 512 threads = 8 waves (2r x 4c),
// wave tile 64r x 64c as 2x2 of 32x32x16 MFMA. In-place 128 x LDH buffer.
__global__ __launch_bounds__(512, 4) void pairnet(
        const float* __restrict__ A, const float* __restrict__ B,
        const _Float16* __restrict__ Wt,
        const float* __restrict__ b2, const float* __restrict__ b3,
        const float* __restrict__ b4, float* __restrict__ pooled4) {
    __shared__ _Float16 hb[128 * LDH];         // 67.6 KB -> 2 blocks/CU

    int blk  = blockIdx.x;
    int half = blk & 1;
    int bss  = blk >> 1;                       // (b*20+s1)*20+s2
    int s2   = bss % 20;
    int s1   = (bss / 20) % 20;
    int b    = bss / 400;
    int tid  = threadIdx.x;

    // ---- layer 1: h1 = relu(A[b,s2,p2] + B[b,s1,p1]), fp32 -> f16 into hb ----
    const float* Abase = A + (b * 20 + s2) * 16 * 256;
    const float* Bbase = B + ((b * 20 + s1) * 16 + half * 8) * 256;
#pragma unroll
    for (int it = 0; it < 8; it++) {
        int u = it * 512 + tid;            // 0..4095 8-col units
        int r = u >> 5;                    // row 0..127 (= p1loc*16 + p2)
        int c = (u & 31) * 8;              // col
        const float* Ap = Abase + (r & 15) * 256 + c;
        const float* Bp = Bbase + (r >> 4) * 256 + c;
        float4 a0 = *(const float4*)(Ap);
        float4 a1 = *(const float4*)(Ap + 4);
        float4 b0 = *(const float4*)(Bp);
        float4 b1 = *(const float4*)(Bp + 4);
        f16x8 hv;
        hv[0] = (_Float16)fmaxf(a0.x + b0.x, 0.f);
        hv[1] = (_Float16)fmaxf(a0.y + b0.y, 0.f);
        hv[2] = (_Float16)fmaxf(a0.z + b0.z, 0.f);
        hv[3] = (_Float16)fmaxf(a0.w + b0.w, 0.f);
        hv[4] = (_Float16)fmaxf(a1.x + b1.x, 0.f);
        hv[5] = (_Float16)fmaxf(a1.y + b1.y, 0.f);
        hv[6] = (_Float16)fmaxf(a1.z + b1.z, 0.f);
        hv[7] = (_Float16)fmaxf(a1.w + b1.w, 0.f);
        *(f16x8*)(hb + r * LDH + c) = hv;
    }

    int wid = tid >> 6, lane = tid & 63;
    int row0 = (wid >> 2) * 64;            // wave: rows row0..row0+63
    int cg0  = (wid & 3) * 2;              // two 32-col groups
    int col0 = (wid & 3) * 64;
    int l31 = lane & 31, hi = lane >> 5;

    const _Float16* abase = hb + (row0 + l31) * LDH + hi * 8;

    // prefetch L=0 ks=0 W frags (independent of LDS) before the barrier
    const _Float16* wb0 = Wt + (size_t)(cg0 * 16) * 512 + lane * 8;
    f16x8 pw0 = *(const f16x8*)(wb0);
    f16x8 pw1 = *(const f16x8*)(wb0 + 16 * 512);
    __syncthreads();

#pragma unroll
    for (int L = 0; L < 3; L++) {
        const float* bias = (L == 0) ? b2 : (L == 1) ? b3 : b4;
        const _Float16* wL = Wt + (size_t)((L * 8 + cg0) * 16) * 512 + lane * 8;

        f32x16 acc00{}, acc01{}, acc10{}, acc11{};
        f16x8 cw0 = pw0, cw1 = pw1;
        f16x8 ca0 = *(const f16x8*)(abase);
        f16x8 ca1 = *(const f16x8*)(abase + 32 * LDH);
#pragma unroll
        for (int ks = 0; ks < 16; ks++) {
            f16x8 nw0, nw1, na0, na1;
            if (ks < 15) {                 // register double-buffer next k-step
                nw0 = *(const f16x8*)(wL + (ks + 1) * 512);
                nw1 = *(const f16x8*)(wL + (16 + ks + 1) * 512);
                na0 = *(const f16x8*)(abase + (ks + 1) * 16);
                na1 = *(const f16x8*)(abase + 32 * LDH + (ks + 1) * 16);
            }
            // swapped operands -> D^T: reg r of acc[mi][ni] is
            // row = row0+32*mi+l31, col = col0+32*ni+8*(r>>2)+4*hi+(r&3)
            acc00 = __builtin_amdgcn_mfma_f32_32x32x16_f16(cw0, ca0, acc00, 0, 0, 0);
            acc01 = __builtin_amdgcn_mfma_f32_32x32x16_f16(cw1, ca0, acc01, 0, 0, 0);
            acc10 = __builtin_amdgcn_mfma_f32_32x32x16_f16(cw0, ca1, acc10, 0, 0, 0);
            acc11 = __builtin_amdgcn_mfma_f32_32x32x16_f16(cw1, ca1, acc11, 0, 0, 0);
            cw0 = nw0; cw1 = nw1; ca0 = na0; ca1 = na1;
        }

        if (L < 2) {
            __syncthreads();               // all reads of hb complete
            // prefetch next layer's ks=0 W frags under the epilogue
            const _Float16* wN = Wt + (size_t)(((L + 1) * 8 + cg0) * 16) * 512 + lane * 8;
            pw0 = *(const f16x8*)(wN);
            pw1 = *(const f16x8*)(wN + 16 * 512);
#pragma unroll
            for (int ni = 0; ni < 2; ni++) {
                const f32x16& aN0 = ni ? acc01 : acc00;
                const f32x16& aN1 = ni ? acc11 : acc10;
#pragma unroll
                for (int q = 0; q < 4; q++) {
                    int cb = col0 + 32 * ni + 8 * q + 4 * hi;
                    float4 bv = *(const float4*)(bias + cb);
                    f16x4 h0, h1;
                    h0[0] = (_Float16)fmaxf(aN0[4 * q + 0] + bv.x, 0.f);
                    h0[1] = (_Float16)fmaxf(aN0[4 * q + 1] + bv.y, 0.f);
                    h0[2] = (_Float16)fmaxf(aN0[4 * q + 2] + bv.z, 0.f);
                    h0[3] = (_Float16)fmaxf(aN0[4 * q + 3] + bv.w, 0.f);
                    h1[0] = (_Float16)fmaxf(aN1[4 * q + 0] + bv.x, 0.f);
                    h1[1] = (_Float16)fmaxf(aN1[4 * q + 1] + bv.y, 0.f);
                    h1[2] = (_Float16)fmaxf(aN1[4 * q + 2] + bv.z, 0.f);
                    h1[3] = (_Float16)fmaxf(aN1[4 * q + 3] + bv.w, 0.f);
                    *(f16x4*)(hb + (row0 + l31) * LDH + cb) = h0;
                    *(f16x4*)(hb + (row0 + 32 + l31) * LDH + cb) = h1;
                }
            }
            __syncthreads();               // writes visible
        } else {
            // layer 4: bias+relu, pool the wave's 64 rows:
            // in-thread over mi, then butterfly over l31 (5 steps)
#pragma unroll
            for (int ni = 0; ni < 2; ni++) {
                const f32x16& aN0 = ni ? acc01 : acc00;
                const f32x16& aN1 = ni ? acc11 : acc10;
                float s[16];
#pragma unroll
                for (int q = 0; q < 4; q++) {
                    int cb = col0 + 32 * ni + 8 * q + 4 * hi;
                    float4 bv = *(const float4*)(bias + cb);
                    s[4 * q + 0] = fmaxf(aN0[4 * q + 0] + bv.x, 0.f) + fmaxf(aN1[4 * q + 0] + bv.x, 0.f);
                    s[4 * q + 1] = fmaxf(aN0[4 * q + 1] + bv.y, 0.f) + fmaxf(aN1[4 * q + 1] + bv.y, 0.f);
                    s[4 * q + 2] = fmaxf(aN0[4 * q + 2] + bv.z, 0.f) + fmaxf(aN1[4 * q + 2] + bv.z, 0.f);
                    s[4 * q + 3] = fmaxf(aN0[4 * q + 3] + bv.w, 0.f) + fmaxf(aN1[4 * q + 3] + bv.w, 0.f);
                }
#pragma unroll
                for (int mask = 1; mask <= 16; mask <<= 1)
#pragma unroll
                    for (int r = 0; r < 16; r++) s[r] += __shfl_xor(s[r], mask);
                if (l31 == 0) {
                    int slab = half * 2 + (wid >> 2);
                    float* pp = pooled4 + ((size_t)slab * 800 + bss) * 256;
#pragma unroll
                    for (int q = 0; q < 4; q++) {
                        float4 sv;
                        sv.x = s[4 * q + 0]; sv.y = s[4 * q + 1];
                        sv.z = s[4 * q + 2]; sv.w = s[4 * q + 3];
                        *(float4*)(pp + col0 + 32 * ni + 8 * q + 4 * hi) = sv;
                    }
                }
            }
        }
    }
}

// ---------------- final MLP on pooled [800,256] (sums 4 slabs) ------------------
__global__ void final_mlp(const float* __restrict__ pooled4,
        const float* __restrict__ Wf1, const float* __restrict__ bf1,
        const float* __restrict__ Wf2, const float* __restrict__ bf2,
        const float* __restrict__ Wf3, const float* __restrict__ bf3,
        const float* __restrict__ Wf4, const float* __restrict__ bf4,
        float* __restrict__ out) {
    __shared__ float p[4][256], y[4][256], z[4][256], y3[4][29];
    int r0 = blockIdx.x * 4;
    int t  = threadIdx.x;
    for (int i = t; i < 1024; i += 256) {
        int r = i >> 8, c = i & 255;
        float v = 0.f;
#pragma unroll
        for (int q = 0; q < 4; q++)
            v += pooled4[((size_t)q * 800 + r0 + r) * 256 + c];
        p[r][c] = v;
    }
    __syncthreads();
    float acc[4];
#pragma unroll
    for (int r = 0; r < 4; r++) acc[r] = bf1[t];
    for (int k = 0; k < 256; k++) {
        float w = Wf1[k * 256 + t];
#pragma unroll
        for (int r = 0; r < 4; r++) acc[r] += p[r][k] * w;
    }
#pragma unroll
    for (int r = 0; r < 4; r++) y[r][t] = fmaxf(acc[r], 0.f);
    __syncthreads();
#pragma unroll
    for (int r = 0; r < 4; r++) acc[r] = bf2[t];
    for (int k = 0; k < 256; k++) {
        float w = Wf2[k * 256 + t];
#pragma unroll
        for (int r = 0; r < 4; r++) acc[r] += y[r][k] * w;
    }
#pragma unroll
    for (int r = 0; r < 4; r++) z[r][t] = fmaxf(acc[r], 0.f);
    __syncthreads();
    if (t < 116) {
        int r = t / 29, c = t % 29;
        float a = bf3[c];
        for (int k = 0; k < 256; k++) a += z[r][k] * Wf3[k * 29 + c];
        y3[r][c] = fmaxf(a, 0.f);
    }
    __syncthreads();
    if (t < 4) {
        float zz = bf4[0];
#pragma unroll
        for (int c = 0; c < 29; c++) zz += y3[t][c] * Wf4[c];
        out[r0 + t] = 1.f / (1.f + expf(-zz));
    }
}

extern "C" void kernel_launch(void* const* d_in, const int* in_sizes, int n_in,
                              void* d_out, int out_size, void* d_ws, size_t ws_size,
                              hipStream_t stream) {
    const float* x   = (const float*)d_in[0];
    const float* W1  = (const float*)d_in[1];
    const float* b1  = (const float*)d_in[2];
    const float* W2  = (const float*)d_in[3];
    const float* b2  = (const float*)d_in[4];
    const float* W3  = (const float*)d_in[5];
    const float* b3  = (const float*)d_in[6];
    const float* W4  = (const float*)d_in[7];
    const float* b4  = (const float*)d_in[8];
    const float* Wf1 = (const float*)d_in[9];
    const float* bf1 = (const float*)d_in[10];
    const float* Wf2 = (const float*)d_in[11];
    const float* bf2 = (const float*)d_in[12];
    const float* Wf3 = (const float*)d_in[13];
    const float* bf3 = (const float*)d_in[14];
    const float* Wf4 = (const float*)d_in[15];
    const float* bf4 = (const float*)d_in[16];

    float* A       = (float*)d_ws;                     // 640*256 f32
    float* B       = A + 640 * 256;                    // 640*256 f32
    float* pooled4 = B + 640 * 256;                    // 4*800*256 f32
    _Float16* Wt   = (_Float16*)(pooled4 + 4 * 800 * 256); // 384 frags * 512 f16

    prep<<<544, 512, 0, stream>>>(x, W1, b1, W2, W3, W4, A, B, Wt);
    pairnet<<<1600, 512, 0, stream>>>(A, B, Wt, b2, b3, b4, pooled4);
    final_mlp<<<200, 256, 0, stream>>>(pooled4, Wf1, bf1, Wf2, bf2, Wf3, bf3, Wf4, bf4,
                                       (float*)d_out);
}

// Round 7
// 122.539 us; speedup vs baseline: 1.1409x; 1.1409x over previous
//
#include <hip/hip_runtime.h>
#include <hip/hip_bf16.h>
#include <math.h>

typedef _Float16 f16x8 __attribute__((ext_vector_type(8)));
typedef _Float16 f16x4 __attribute__((ext_vector_type(4)));
typedef float f32x4 __attribute__((ext_vector_type(4)));

#define LDH 264  // 256 + 8 f16 pad -> row stride 132 dwords (4-bank rotation):
                 // b128 reads / 16B writes / 8B epilogue stores all bank-balanced

// ---------------- fused prep ----------------------------------------------------
// blocks 0..383: W2/W3/W4 -> f16 fragment-contiguous (16x16 layout, as R4)
//   frag = (L*16+cg)*8+kk ; col = cg*16+(l&15) ; k = kk*32+(l>>4)*8+e
// blocks 384..543: A/B projection with 8-deep unrolled W1 loads
__global__ void prep(const float* __restrict__ x, const float* __restrict__ W1,
                     const float* __restrict__ b1,
                     const float* __restrict__ W2, const float* __restrict__ W3,
                     const float* __restrict__ W4,
                     float* __restrict__ A, float* __restrict__ B,
                     _Float16* __restrict__ Wt) {
    __shared__ float xs[258 * 4];
    if (blockIdx.x < 384) {
        int blk = blockIdx.x, t = threadIdx.x;
        int kk = blk & 7, cg = (blk >> 3) & 15, L = blk >> 7;
        int l = t >> 3, e = t & 7;
        int col = cg * 16 + (l & 15);
        int k   = kk * 32 + (l >> 4) * 8 + e;
        const float* W = (L == 0) ? W2 : (L == 1) ? W3 : W4;
        Wt[blk * 512 + t] = (_Float16)W[k * 256 + col];
        return;
    }
    int blk = blockIdx.x - 384;
    int bs = blk >> 2, pg = blk & 3;           // 4 p-values per block
    for (int i = threadIdx.x; i < 1024; i += 512) {
        int c = i >> 2, pp = i & 3;
        xs[i] = x[bs * 4096 + c * 16 + pg * 4 + pp];
    }
    if (threadIdx.x < 8) {
        int pp = threadIdx.x & 3, c = 256 + (threadIdx.x >> 2);
        int p = pg * 4 + pp;
        xs[c * 4 + pp] = (float)((c == 256) ? (p >> 2) : (p & 3)) * 0.25f;
    }
    __syncthreads();
    int half = threadIdx.x >> 8;               // 0 -> A, 1 -> B
    int col  = threadIdx.x & 255;
    float acc[4] = {0.f, 0.f, 0.f, 0.f};
    const float* Wp = W1 + half * 258 * 256 + col;
#pragma unroll 1
    for (int c0 = 0; c0 < 256; c0 += 8) {
        float w[8];
#pragma unroll
        for (int j = 0; j < 8; j++) w[j] = Wp[(c0 + j) * 256];
#pragma unroll
        for (int j = 0; j < 8; j++)
#pragma unroll
            for (int pp = 0; pp < 4; pp++) acc[pp] += xs[(c0 + j) * 4 + pp] * w[j];
    }
#pragma unroll
    for (int c = 256; c < 258; c++) {
        float w = Wp[c * 256];
#pragma unroll
        for (int pp = 0; pp < 4; pp++) acc[pp] += xs[c * 4 + pp] * w;
    }
    float* out = half ? B : A;
    float bias = half ? 0.f : b1[col];         // fold b1 into A once
#pragma unroll
    for (int pp = 0; pp < 4; pp++)
        out[(bs * 16 + pg * 4 + pp) * 256 + col] = acc[pp] + bias;
}

// ---------------- the big fused kernel ------------------------------------------
// grid 3200 = (b,s1,s2) x 4 row-quarters; 256 threads = 4 waves, each 64r x 64c.
// Row-quarters are fully independent through layers 2-4 -> barrier domain is
// only the 4 waves sharing these 64 rows. LDS 33.8 KB -> 4 blocks/CU.
__global__ __launch_bounds__(256, 4) void pairnet(
        const float* __restrict__ A, const float* __restrict__ B,
        const _Float16* __restrict__ Wt,
        const float* __restrict__ b2, const float* __restrict__ b3,
        const float* __restrict__ b4, float* __restrict__ pooled4) {
    __shared__ _Float16 hb[64 * LDH];          // 33.8 KB

    int blk = blockIdx.x;
    int qtr = blk & 3;
    int bss = blk >> 2;                        // (b*20+s1)*20+s2
    int s2  = bss % 20;
    int s1  = (bss / 20) % 20;
    int b   = bss / 400;
    int tid = threadIdx.x;

    // ---- layer 1: h1 = relu(A[b,s2,p2] + B[b,s1,p1]), fp32 -> f16 into hb ----
    // 8-col units, b128 LDS writes (all 32 banks covered)
    const float* Abase = A + (b * 20 + s2) * 16 * 256;
    const float* Bbase = B + ((b * 20 + s1) * 16 + qtr * 4) * 256;
#pragma unroll
    for (int it = 0; it < 8; it++) {
        int u = it * 256 + tid;            // 0..2047 8-col units
        int r = u >> 5;                    // row 0..63 (= p1loc*16 + p2)
        int c = (u & 31) * 8;              // col
        const float* Ap = Abase + (r & 15) * 256 + c;
        const float* Bp = Bbase + (r >> 4) * 256 + c;
        float4 a0 = *(const float4*)(Ap);
        float4 a1 = *(const float4*)(Ap + 4);
        float4 b0 = *(const float4*)(Bp);
        float4 b1 = *(const float4*)(Bp + 4);
        f16x8 hv;
        hv[0] = (_Float16)fmaxf(a0.x + b0.x, 0.f);
        hv[1] = (_Float16)fmaxf(a0.y + b0.y, 0.f);
        hv[2] = (_Float16)fmaxf(a0.z + b0.z, 0.f);
        hv[3] = (_Float16)fmaxf(a0.w + b0.w, 0.f);
        hv[4] = (_Float16)fmaxf(a1.x + b1.x, 0.f);
        hv[5] = (_Float16)fmaxf(a1.y + b1.y, 0.f);
        hv[6] = (_Float16)fmaxf(a1.z + b1.z, 0.f);
        hv[7] = (_Float16)fmaxf(a1.w + b1.w, 0.f);
        *(f16x8*)(hb + r * LDH + c) = hv;
    }
    __syncthreads();

    int wid = tid >> 6, lane = tid & 63;
    int col0 = wid * 64;                   // wave owns 64 cols x all 64 rows
    int lr = lane & 15, lk = lane >> 4;

#pragma unroll
    for (int L = 0; L < 3; L++) {
        const float* bias = (L == 0) ? b2 : (L == 1) ? b3 : b4;
        // fragment-contiguous W base for this wave's 4 col-groups
        const _Float16* wb = Wt + (size_t)((L * 16 + wid * 4) * 8) * 512 + lane * 8;

        f32x4 acc[4][4];
#pragma unroll
        for (int m = 0; m < 4; m++)
#pragma unroll
            for (int n = 0; n < 4; n++) acc[m][n] = (f32x4){0.f, 0.f, 0.f, 0.f};

#pragma unroll
        for (int kk = 0; kk < 8; kk++) {
            f16x8 w[4], a[4];
#pragma unroll
            for (int n = 0; n < 4; n++)
                w[n] = *(const f16x8*)(wb + (n * 8 + kk) * 512);
#pragma unroll
            for (int m = 0; m < 4; m++)
                a[m] = *(const f16x8*)(hb + (16 * m + lr) * LDH + kk * 32 + 8 * lk);
            // swapped operands -> transposed D: thread holds row 16m+lr,
            // cols col0+16n+4lk+{0..3}
#pragma unroll
            for (int m = 0; m < 4; m++)
#pragma unroll
                for (int n = 0; n < 4; n++)
                    acc[m][n] = __builtin_amdgcn_mfma_f32_16x16x32_f16(
                        w[n], a[m], acc[m][n], 0, 0, 0);
        }

        if (L < 2) {
            __syncthreads();               // all reads of hb complete
#pragma unroll
            for (int n = 0; n < 4; n++) {
                int cb = col0 + 16 * n + 4 * lk;
                float4 b4v = *(const float4*)(bias + cb);
#pragma unroll
                for (int m = 0; m < 4; m++) {
                    int row = 16 * m + lr;
                    f16x4 hv;
                    hv[0] = (_Float16)fmaxf(acc[m][n][0] + b4v.x, 0.f);
                    hv[1] = (_Float16)fmaxf(acc[m][n][1] + b4v.y, 0.f);
                    hv[2] = (_Float16)fmaxf(acc[m][n][2] + b4v.z, 0.f);
                    hv[3] = (_Float16)fmaxf(acc[m][n][3] + b4v.w, 0.f);
                    *(f16x4*)(hb + row * LDH + cb) = hv;
                }
            }
            __syncthreads();               // writes visible
        } else {
            // layer 4: bias+relu, pool all 64 rows (m in-thread, lr butterfly)
#pragma unroll
            for (int n = 0; n < 4; n++) {
                int cb = col0 + 16 * n + 4 * lk;
                float4 b4v = *(const float4*)(bias + cb);
                f32x4 s = (f32x4){0.f, 0.f, 0.f, 0.f};
#pragma unroll
                for (int m = 0; m < 4; m++) {
                    s[0] += fmaxf(acc[m][n][0] + b4v.x, 0.f);
                    s[1] += fmaxf(acc[m][n][1] + b4v.y, 0.f);
                    s[2] += fmaxf(acc[m][n][2] + b4v.z, 0.f);
                    s[3] += fmaxf(acc[m][n][3] + b4v.w, 0.f);
                }
#pragma unroll
                for (int mask = 1; mask <= 8; mask <<= 1) {
#pragma unroll
                    for (int c = 0; c < 4; c++) s[c] += __shfl_xor(s[c], mask);
                }
                if (lr == 0) {
                    float4 sv; sv.x = s[0]; sv.y = s[1]; sv.z = s[2]; sv.w = s[3];
                    *(float4*)(pooled4 + ((size_t)qtr * 800 + bss) * 256 + cb) = sv;
                }
            }
        }
    }
}

// ---------------- final MLP on pooled [800,256] (sums 4 slabs) ------------------
__global__ void final_mlp(const float* __restrict__ pooled4,
        const float* __restrict__ Wf1, const float* __restrict__ bf1,
        const float* __restrict__ Wf2, const float* __restrict__ bf2,
        const float* __restrict__ Wf3, const float* __restrict__ bf3,
        const float* __restrict__ Wf4, const float* __restrict__ bf4,
        float* __restrict__ out) {
    __shared__ float p[4][256], y[4][256], z[4][256], y3[4][29];
    int r0 = blockIdx.x * 4;
    int t  = threadIdx.x;
    for (int i = t; i < 1024; i += 256) {
        int r = i >> 8, c = i & 255;
        float v = 0.f;
#pragma unroll
        for (int q = 0; q < 4; q++)
            v += pooled4[((size_t)q * 800 + r0 + r) * 256 + c];
        p[r][c] = v;
    }
    __syncthreads();
    float acc[4];
#pragma unroll
    for (int r = 0; r < 4; r++) acc[r] = bf1[t];
#pragma unroll 1
    for (int k0 = 0; k0 < 256; k0 += 8) {
        float w[8];
#pragma unroll
        for (int j = 0; j < 8; j++) w[j] = Wf1[(k0 + j) * 256 + t];
#pragma unroll
        for (int j = 0; j < 8; j++)
#pragma unroll
            for (int r = 0; r < 4; r++) acc[r] += p[r][k0 + j] * w[j];
    }
#pragma unroll
    for (int r = 0; r < 4; r++) y[r][t] = fmaxf(acc[r], 0.f);
    __syncthreads();
#pragma unroll
    for (int r = 0; r < 4; r++) acc[r] = bf2[t];
#pragma unroll 1
    for (int k0 = 0; k0 < 256; k0 += 8) {
        float w[8];
#pragma unroll
        for (int j = 0; j < 8; j++) w[j] = Wf2[(k0 + j) * 256 + t];
#pragma unroll
        for (int j = 0; j < 8; j++)
#pragma unroll
            for (int r = 0; r < 4; r++) acc[r] += y[r][k0 + j] * w[j];
    }
#pragma unroll
    for (int r = 0; r < 4; r++) z[r][t] = fmaxf(acc[r], 0.f);
    __syncthreads();
    if (t < 116) {
        int r = t / 29, c = t % 29;
        float a = bf3[c];
#pragma unroll 1
        for (int k0 = 0; k0 < 256; k0 += 8) {
            float w[8];
#pragma unroll
            for (int j = 0; j < 8; j++) w[j] = Wf3[(k0 + j) * 29 + c];
#pragma unroll
            for (int j = 0; j < 8; j++) a += z[r][k0 + j] * w[j];
        }
        y3[r][c] = fmaxf(a, 0.f);
    }
    __syncthreads();
    if (t < 4) {
        float zz = bf4[0];
#pragma unroll
        for (int c = 0; c < 29; c++) zz += y3[t][c] * Wf4[c];
        out[r0 + t] = 1.f / (1.f + expf(-zz));
    }
}

extern "C" void kernel_launch(void* const* d_in, const int* in_sizes, int n_in,
                              void* d_out, int out_size, void* d_ws, size_t ws_size,
                              hipStream_t stream) {
    const float* x   = (const float*)d_in[0];
    const float* W1  = (const float*)d_in[1];
    const float* b1  = (const float*)d_in[2];
    const float* W2  = (const float*)d_in[3];
    const float* b2  = (const float*)d_in[4];
    const float* W3  = (const float*)d_in[5];
    const float* b3  = (const float*)d_in[6];
    const float* W4  = (const float*)d_in[7];
    const float* b4  = (const float*)d_in[8];
    const float* Wf1 = (const float*)d_in[9];
    const float* bf1 = (const float*)d_in[10];
    const float* Wf2 = (const float*)d_in[11];
    const float* bf2 = (const float*)d_in[12];
    const float* Wf3 = (const float*)d_in[13];
    const float* bf3 = (const float*)d_in[14];
    const float* Wf4 = (const float*)d_in[15];
    const float* bf4 = (const float*)d_in[16];

    float* A       = (float*)d_ws;                     // 640*256 f32
    float* B       = A + 640 * 256;                    // 640*256 f32
    float* pooled4 = B + 640 * 256;                    // 4*800*256 f32
    _Float16* Wt   = (_Float16*)(pooled4 + 4 * 800 * 256); // 384 frags * 512 f16

    prep<<<544, 512, 0, stream>>>(x, W1, b1, W2, W3, W4, A, B, Wt);
    pairnet<<<3200, 256, 0, stream>>>(A, B, Wt, b2, b3, b4, pooled4);
    final_mlp<<<200, 256, 0, stream>>>(pooled4, Wf1, bf1, Wf2, bf2, Wf3, bf3, Wf4, bf4,
                                       (float*)d_out);
}